// Round 4
// baseline (142868.848 us; speedup 1.0000x reference)
//
#include <hip/hip_runtime.h>
#include <hip/hip_bf16.h>
#include <cstddef>

// ---------------------------------------------------------------------------
// Round 4: fp32 VALU clone with FLOAT32 stores (the round-1..3 failure was
// writing bf16 into an fp32 d_out — reference output dtype is float32).
// Correctness anchor: no MFMA, fp32 recurrence, masked freeze, packing from
// inverting the actual pack_idx input.
// ---------------------------------------------------------------------------

__global__ void inv_init(int* inv) {
  int i = blockIdx.x * 256 + threadIdx.x;
  if (i < 512 * 256) inv[i] = -1;
}

__global__ void inv_fill(const int* __restrict__ pack_idx, int* __restrict__ inv, int N) {
  int j = blockIdx.x * 256 + threadIdx.x;
  if (j < N) inv[pack_idx[j]] = j;
}

__device__ __forceinline__ float sigmf_(float x) { return 1.0f / (1.0f + expf(-x)); }

__launch_bounds__(1024, 1)
__global__ void clone_main(const float* __restrict__ features,
                           const float* __restrict__ W_f2h, const float* __restrict__ b_f2h,
                           const float* __restrict__ W_ih, const float* __restrict__ W_hh,
                           const float* __restrict__ b_ih, const float* __restrict__ b_hh,
                           const float* __restrict__ p1W1, const float* __restrict__ p1b1,
                           const float* __restrict__ p1W2, const float* __restrict__ p1b2,
                           const float* __restrict__ p2W1, const float* __restrict__ p2b1,
                           const float* __restrict__ p2W2, const float* __restrict__ p2b2,
                           const float* __restrict__ offW1, const float* __restrict__ offb1,
                           const float* __restrict__ offW2, const float* __restrict__ offb2,
                           const int* __restrict__ lens, const int* __restrict__ inv,
                           float* __restrict__ out, int N) {
  __shared__ float xs[4][128];
  __shared__ float hs[4][512];
  __shared__ float th[4][1536];   // first 512 cols double as c0 staging at init
  __shared__ int lens_s[4];

  const int tid = threadIdx.x;
  const int m = tid & 3;          // local row 0..3
  const int cq = tid >> 2;        // 0..255 column slot
  const int bb = blockIdx.x;
  const int row = bb * 4 + m;     // global batch row

  if (tid < 4) lens_s[tid] = lens[bb * 4 + tid];
  if (cq < 128) xs[m][cq] = 0.f;

  // ---- init: hid = features @ W_f2h^T + b_f2h; even cols -> h0, odd -> c0 ----
  {
    const float* fr = features + (size_t)row * 256;
    for (int k = 0; k < 4; k++) {
      int col = cq + 256 * k;
      const float* wr = W_f2h + (size_t)col * 256;
      float a0 = 0.f, a1 = 0.f, a2 = 0.f, a3 = 0.f;
      for (int kk = 0; kk < 256; kk += 4) {
        a0 += fr[kk] * wr[kk];
        a1 += fr[kk + 1] * wr[kk + 1];
        a2 += fr[kk + 2] * wr[kk + 2];
        a3 += fr[kk + 3] * wr[kk + 3];
      }
      float acc = b_f2h[col] + ((a0 + a1) + (a2 + a3));
      if (col & 1) th[m][col >> 1] = acc;  // c0 staging
      else hs[m][col >> 1] = acc;          // h0
    }
  }
  __syncthreads();

  float creg[2];
  creg[0] = th[m][cq];
  creg[1] = th[m][cq + 256];
  int steps = max(max(lens_s[0], lens_s[1]), max(lens_s[2], lens_s[3]));

  const size_t base1 = (size_t)N * 128;
  const size_t base2 = 2 * base1;
  const size_t base3 = base2 + (size_t)N;

  for (int t = 0; t < steps; t++) {
    const bool mk = t < lens_s[m];
    float hn[2];

    // ---- phase 1: gates + LSTM cell (thread owns (m, cq) and (m, cq+256)) ----
    for (int k = 0; k < 2; k++) {
      int u = cq + 256 * k;
      float ai = b_ih[u] + b_hh[u];
      float af = b_ih[512 + u] + b_hh[512 + u];
      float ag = b_ih[1024 + u] + b_hh[1024 + u];
      float ao = b_ih[1536 + u] + b_hh[1536 + u];
      {
        const float* wi = W_ih + (size_t)u * 128;
        const float* wf = W_ih + (size_t)(512 + u) * 128;
        const float* wg = W_ih + (size_t)(1024 + u) * 128;
        const float* wo = W_ih + (size_t)(1536 + u) * 128;
        for (int kk = 0; kk < 128; kk++) {
          float xx = xs[m][kk];
          ai += xx * wi[kk];
          af += xx * wf[kk];
          ag += xx * wg[kk];
          ao += xx * wo[kk];
        }
      }
      {
        const float* vi = W_hh + (size_t)u * 512;
        const float* vf = W_hh + (size_t)(512 + u) * 512;
        const float* vg = W_hh + (size_t)(1024 + u) * 512;
        const float* vo = W_hh + (size_t)(1536 + u) * 512;
        for (int kk = 0; kk < 512; kk++) {
          float hh = hs[m][kk];
          ai += hh * vi[kk];
          af += hh * vf[kk];
          ag += hh * vg[kk];
          ao += hh * vo[kk];
        }
      }
      float cn = sigmf_(af) * creg[k] + sigmf_(ai) * tanhf(ag);
      if (mk) creg[k] = cn;
      hn[k] = sigmf_(ao) * tanhf(cn);
    }
    __syncthreads();  // all reads of hs done
    if (mk) {
      hs[m][cq] = hn[0];
      hs[m][cq + 256] = hn[1];
    }
    __syncthreads();  // h(t) ready

    // ---- phase 2: th = tanh(h @ W1^T + b1), stacked [p1 | p2 | off] ----
    for (int k = 0; k < 6; k++) {
      int j = cq + 256 * k;
      const float* w1;
      float b1;
      if (j < 512) { w1 = p1W1 + (size_t)j * 512; b1 = p1b1[j]; }
      else if (j < 1024) { w1 = p2W1 + (size_t)(j - 512) * 512; b1 = p2b1[j - 512]; }
      else { w1 = offW1 + (size_t)(j - 1024) * 512; b1 = offb1[j - 1024]; }
      float a0 = 0.f, a1 = 0.f, a2 = 0.f, a3 = 0.f;
      for (int kk = 0; kk < 512; kk += 4) {
        a0 += hs[m][kk] * w1[kk];
        a1 += hs[m][kk + 1] * w1[kk + 1];
        a2 += hs[m][kk + 2] * w1[kk + 2];
        a3 += hs[m][kk + 3] * w1[kk + 3];
      }
      th[m][j] = tanhf(b1 + ((a0 + a1) + (a2 + a3)));
    }
    __syncthreads();  // th ready

    // ---- phase 3: p1/p2/offsets outputs + x(t+1) = p1(t) ----
    const int pos = inv[t * 256 + row];
    for (int k = 0; k < 2; k++) {
      int nn = cq + 256 * k;
      if (nn < 128) {
        const float* w2 = p1W2 + (size_t)nn * 512;
        float a0 = 0.f, a1 = 0.f, a2 = 0.f, a3 = 0.f;
        for (int kk = 0; kk < 512; kk += 4) {
          a0 += th[m][kk] * w2[kk];
          a1 += th[m][kk + 1] * w2[kk + 1];
          a2 += th[m][kk + 2] * w2[kk + 2];
          a3 += th[m][kk + 3] * w2[kk + 3];
        }
        float acc = p1b2[nn] + ((a0 + a1) + (a2 + a3));
        xs[m][nn] = acc;  // x feedback: always (matches ref carry)
        if (pos >= 0) {
          out[(size_t)pos * 128 + nn] = acc;            // flat_p1
          out[base3 + (size_t)pos * 128 + nn] = acc;    // flat_out (= flat_p1)
        }
      } else if (nn < 256) {
        int n2 = nn - 128;
        const float* w2 = p2W2 + (size_t)n2 * 512;
        float a0 = 0.f, a1 = 0.f, a2 = 0.f, a3 = 0.f;
        for (int kk = 0; kk < 512; kk += 4) {
          a0 += th[m][512 + kk] * w2[kk];
          a1 += th[m][512 + kk + 1] * w2[kk + 1];
          a2 += th[m][512 + kk + 2] * w2[kk + 2];
          a3 += th[m][512 + kk + 3] * w2[kk + 3];
        }
        float acc = p2b2[n2] + ((a0 + a1) + (a2 + a3));
        if (pos >= 0) out[base1 + (size_t)pos * 128 + n2] = acc;
      } else if (nn == 256) {
        float a0 = 0.f, a1 = 0.f, a2 = 0.f, a3 = 0.f;
        for (int kk = 0; kk < 512; kk += 4) {
          a0 += th[m][1024 + kk] * offW2[kk];
          a1 += th[m][1024 + kk + 1] * offW2[kk + 1];
          a2 += th[m][1024 + kk + 2] * offW2[kk + 2];
          a3 += th[m][1024 + kk + 3] * offW2[kk + 3];
        }
        float acc = offb2[0] + ((a0 + a1) + (a2 + a3));
        if (pos >= 0) out[base2 + (size_t)pos] = acc;
      }
    }
    __syncthreads();  // x ready for next step's phase 1
  }
}

extern "C" void kernel_launch(void* const* d_in, const int* in_sizes, int n_in,
                              void* d_out, int out_size, void* d_ws, size_t ws_size,
                              hipStream_t stream) {
  const float* features = (const float*)d_in[0];
  const float* W_f2h = (const float*)d_in[1];
  const float* b_f2h = (const float*)d_in[2];
  const float* W_ih = (const float*)d_in[3];
  const float* W_hh = (const float*)d_in[4];
  const float* b_ih = (const float*)d_in[5];
  const float* b_hh = (const float*)d_in[6];
  const float* p1W1 = (const float*)d_in[7];
  const float* p1b1 = (const float*)d_in[8];
  const float* p1W2 = (const float*)d_in[9];
  const float* p1b2 = (const float*)d_in[10];
  const float* p2W1 = (const float*)d_in[11];
  const float* p2b1 = (const float*)d_in[12];
  const float* p2W2 = (const float*)d_in[13];
  const float* p2b2 = (const float*)d_in[14];
  const float* offW1 = (const float*)d_in[15];
  const float* offb1 = (const float*)d_in[16];
  const float* offW2 = (const float*)d_in[17];
  const float* offb2 = (const float*)d_in[18];
  const int* lens = (const int*)d_in[19];
  const int* pack_idx = (const int*)d_in[20];
  const int N = in_sizes[20];
  int* inv = (int*)d_ws;  // 512*256 ints = 512 KB

  inv_init<<<512, 256, 0, stream>>>(inv);
  inv_fill<<<(N + 255) / 256, 256, 0, stream>>>(pack_idx, inv, N);
  clone_main<<<64, 1024, 0, stream>>>(features, W_f2h, b_f2h, W_ih, W_hh, b_ih, b_hh,
                                      p1W1, p1b1, p1W2, p1b2, p2W1, p2b1, p2W2, p2b2,
                                      offW1, offb1, offW2, offb2, lens, inv,
                                      (float*)d_out, N);
}

// Round 5
// 21531.259 us; speedup vs baseline: 6.6354x; 6.6354x over previous
//
#include <hip/hip_runtime.h>
#include <hip/hip_bf16.h>
#include <cstddef>

// ---------------------------------------------------------------------------
// Round 5: MFMA persistent-group design.
// 16 groups (16 rows each) x 16 blocks; weights bf16 fragment-packed in ws;
// x-feedback folded into the gates GEMM (Wcombo = W_ih @ p1W2, K=1024);
// fp32 cell/c-state; bf16 h/th exchanged via ws; 2 device barriers per step.
// Output addressing via inv(pack_idx) and fp32 stores (validated round 4).
// ---------------------------------------------------------------------------

typedef __attribute__((ext_vector_type(8))) __bf16 bf16x8;
typedef __attribute__((ext_vector_type(8))) short s16x8;
typedef __attribute__((ext_vector_type(4))) float f32x4;

static constexpr int C_BLK = 16;  // blocks per group

// ---- ws layout (bytes) ----
static constexpr size_t WS_WG = 0;         // [128 tiles][32 kc][64][8] bf16 = 4 MiB
static constexpr size_t WS_WH = 4194304;   // [96 tiles][16 kc][64][8]  = 1.5 MiB
static constexpr size_t WS_WO = 5767168;   // [17 tiles][16 kc][64][8]
static constexpr size_t WS_BNF = 6045696;  // float[2048]  b_ih+b_hh
static constexpr size_t WS_BCM = 6053888;  // float[2048]  + W_ih@p1b2
static constexpr size_t WS_BH = 6062080;   // float[1536]
static constexpr size_t WS_BO = 6068224;   // float[272] (padded)
static constexpr size_t WS_BAR = 6070272;  // 16 * 128B barrier counters
static constexpr size_t WS_INV = 6072320;  // int[512*256]
static constexpr size_t WS_GRP = 6596608;  // 16 groups * 98304B
static constexpr size_t GRPB = 98304;
// within a group, offsets in SHORTS:
static constexpr int TH1_O = 16384;  // h: [2 buf][16 m][512] at 0
static constexpr int TH2_O = 32768;  // th1: [2 buf][16 m][512]
static constexpr int OFFT_O = 40960; // th2: [16][512]; thoff: [16][512]

__device__ __forceinline__ unsigned short f2bf(float v) {
  __hip_bfloat16 h = __float2bfloat16(v);
  return *reinterpret_cast<unsigned short*>(&h);
}
__device__ __forceinline__ f32x4 mfma16(s16x8 a, s16x8 b, f32x4 c) {
  return __builtin_amdgcn_mfma_f32_16x16x32_bf16(
      __builtin_bit_cast(bf16x8, a), __builtin_bit_cast(bf16x8, b), c, 0, 0, 0);
}
__device__ __forceinline__ s16x8 ld8(const short* p) { return *(const s16x8*)p; }
__device__ __forceinline__ float sigm(float x) { return 1.0f / (1.0f + expf(-x)); }

__global__ void inv_init(int* inv) {
  int i = blockIdx.x * 256 + threadIdx.x;
  if (i < 512 * 256) inv[i] = -1;
}
__global__ void inv_fill(const int* __restrict__ pack_idx, int* __restrict__ inv, int N) {
  int j = blockIdx.x * 256 + threadIdx.x;
  if (j < N) inv[pack_idx[j]] = j;
}

// ---------------- prep: bf16 fragment-order weights ---------------------------
__global__ void prep_w(const float* __restrict__ Whh, const float* __restrict__ Wih,
                       const float* __restrict__ p1W2, const float* __restrict__ p1W1,
                       const float* __restrict__ p2W1, const float* __restrict__ offW1,
                       const float* __restrict__ p2W2, const float* __restrict__ offW2,
                       char* __restrict__ ws) {
  int s = blockIdx.x * 256 + threadIdx.x;
  if (s < 262144) {  // Wg: [2048 n][1024 k] = [Whh | Wcombo=W_ih@p1W2]
    int tile = s >> 11, rem = s & 2047;
    int kc = rem >> 6, lane = rem & 63;
    int n = tile * 16 + (lane & 15);
    int k0 = kc * 32 + ((lane >> 4) << 3);
    s16x8 o;
    if (kc < 16) {
      const float* src = Whh + (size_t)n * 512 + k0;
      for (int i = 0; i < 8; i++) o[i] = (short)f2bf(src[i]);
    } else {
      int c0 = k0 - 512;
      float acc[8] = {0, 0, 0, 0, 0, 0, 0, 0};
      const float* wr = Wih + (size_t)n * 128;
      for (int j = 0; j < 128; j++) {
        float wij = wr[j];
        const float* pr = p1W2 + (size_t)j * 512 + c0;
        for (int i = 0; i < 8; i++) acc[i] += wij * pr[i];
      }
      for (int i = 0; i < 8; i++) o[i] = (short)f2bf(acc[i]);
    }
    *(s16x8*)((short*)(ws + WS_WG) + (size_t)(tile * 32 + kc) * 512 + lane * 8) = o;
  } else if (s < 262144 + 98304) {  // Wh: [1536 n][512 k] = p1W1|p2W1|offW1
    int z = s - 262144;
    int tile = z >> 10, rem = z & 1023;
    int kc = rem >> 6, lane = rem & 63;
    int n = tile * 16 + (lane & 15);
    int k0 = kc * 32 + ((lane >> 4) << 3);
    const float* src = (n < 512) ? p1W1 + (size_t)n * 512
                     : (n < 1024) ? p2W1 + (size_t)(n - 512) * 512
                                  : offW1 + (size_t)(n - 1024) * 512;
    s16x8 o;
    for (int i = 0; i < 8; i++) o[i] = (short)f2bf(src[k0 + i]);
    *(s16x8*)((short*)(ws + WS_WH) + (size_t)(tile * 16 + kc) * 512 + lane * 8) = o;
  } else if (s < 262144 + 98304 + 17408) {  // Wo: [272 n][512 k] = p1W2|p2W2|offW2
    int z = s - 262144 - 98304;
    int tile = z >> 10, rem = z & 1023;
    int kc = rem >> 6, lane = rem & 63;
    int n = tile * 16 + (lane & 15);
    int k0 = kc * 32 + ((lane >> 4) << 3);
    s16x8 o;
    for (int i = 0; i < 8; i++) {
      int k = k0 + i;
      float v = (n < 128) ? p1W2[(size_t)n * 512 + k]
              : (n < 256) ? p2W2[(size_t)(n - 128) * 512 + k]
              : (n == 256) ? offW2[k] : 0.f;
      o[i] = (short)f2bf(v);
    }
    *(s16x8*)((short*)(ws + WS_WO) + (size_t)(tile * 16 + kc) * 512 + lane * 8) = o;
  }
}

// ---------------- prep: biases, barrier counters, th1 buf0 = 0 ---------------
__global__ void prep_misc(const float* __restrict__ b_ih, const float* __restrict__ b_hh,
                          const float* __restrict__ Wih, const float* __restrict__ p1b2,
                          const float* __restrict__ p1b1, const float* __restrict__ p2b1,
                          const float* __restrict__ offb1, const float* __restrict__ p2b2,
                          const float* __restrict__ offb2, char* __restrict__ ws) {
  int i = blockIdx.x * 256 + threadIdx.x;
  if (i < 2048) {
    float bn = b_ih[i] + b_hh[i];
    ((float*)(ws + WS_BNF))[i] = bn;
    float acc = 0.f;
    const float* wr = Wih + (size_t)i * 128;
    for (int j = 0; j < 128; j++) acc += wr[j] * p1b2[j];
    ((float*)(ws + WS_BCM))[i] = bn + acc;
  } else if (i < 3584) {
    int j = i - 2048;
    ((float*)(ws + WS_BH))[j] =
        j < 512 ? p1b1[j] : (j < 1024 ? p2b1[j - 512] : offb1[j - 1024]);
  } else if (i < 3856) {
    int j = i - 3584;
    ((float*)(ws + WS_BO))[j] =
        j < 128 ? p1b2[j] : (j < 256 ? p2b2[j - 128] : (j == 256 ? offb2[0] : 0.f));
  } else if (i < 3872) {
    *(int*)(ws + WS_BAR + (size_t)(i - 3856) * 128) = 0;
  } else if (i < 3872 + 16384) {
    int z = i - 3872;
    int g = z >> 10, r = z & 1023;  // zero th1 buffer 0 (th1_{-1} = 0)
    s16x8 zz = {0, 0, 0, 0, 0, 0, 0, 0};
    *(s16x8*)((short*)(ws + WS_GRP + (size_t)g * GRPB) + TH1_O + (size_t)r * 8) = zz;
  }
}

// ---------------- main persistent kernel -------------------------------------
__launch_bounds__(512, 1)
__global__ void rnn_main(const float* __restrict__ features, const float* __restrict__ Wf2h,
                         const float* __restrict__ bf2h, const int* __restrict__ lens,
                         char* __restrict__ ws, const int* __restrict__ inv,
                         float* __restrict__ out, int N) {
  const int g = blockIdx.x & 15;      // group: blocks g, g+16, ... land on XCD g%8
  const int rank = blockIdx.x >> 4;   // 0..15 within group
  const int tid = threadIdx.x, w = tid >> 6, l = tid & 63, lr = l & 15, hi = l >> 4;

  __shared__ float gacc[4][32][16];   // [gate][block-local n][m]
  __shared__ int lens_s[16];

  const short* Wg = (const short*)(ws + WS_WG);
  const short* Wh = (const short*)(ws + WS_WH);
  const short* Wo = (const short*)(ws + WS_WO);
  const float* bnf = (const float*)(ws + WS_BNF);
  const float* bcm = (const float*)(ws + WS_BCM);
  const float* bh = (const float*)(ws + WS_BH);
  const float* bo = (const float*)(ws + WS_BO);
  int* bar = (int*)(ws + WS_BAR + (size_t)g * 128);
  short* hb_ = (short*)(ws + WS_GRP + (size_t)g * GRPB);  // h [2][16][512]
  short* t1b = hb_ + TH1_O;                               // th1 [2][16][512]
  short* t2b = hb_ + TH2_O;                               // th2 [16][512]
  short* tob = hb_ + OFFT_O;                              // thoff [16][512]

  if (tid < 16) lens_s[tid] = lens[g * 16 + tid];
  __syncthreads();
  int steps = 0;
  for (int i = 0; i < 16; i++) steps = max(steps, lens_s[i]);

  int ep = 0;
  auto gbar = [&]() {
    __syncthreads();
    if (tid == 0) {
      ++ep;
      __threadfence();
      __hip_atomic_fetch_add(bar, 1, __ATOMIC_RELEASE, __HIP_MEMORY_SCOPE_AGENT);
      while (__hip_atomic_load(bar, __ATOMIC_ACQUIRE, __HIP_MEMORY_SCOPE_AGENT) <
             ep * C_BLK)
        __builtin_amdgcn_s_sleep(1);
      __threadfence();
    }
    __syncthreads();
  };

  // ---- init: h0/c0 from features (fp32 VALU); this block's 32-unit slice ----
  const int m_c = tid >> 5, ul_c = tid & 31, u_c = rank * 32 + ul_c;
  float creg;
  {
    const float* fr = features + (size_t)(g * 16 + m_c) * 256;
    const float* w0 = Wf2h + (size_t)(2 * u_c) * 256;
    const float* w1 = w0 + 256;
    float ah = 0.f, ac = 0.f;
    for (int k = 0; k < 256; k++) {
      float fv = fr[k];
      ah += fv * w0[k];
      ac += fv * w1[k];
    }
    ah += bf2h[2 * u_c];
    ac += bf2h[2 * u_c + 1];
    creg = ac;
    hb_[m_c * 512 + u_c] = (short)f2bf(ah);  // buffer 0
  }
  float bnf_r[4], bcm_r[4];
  for (int ga = 0; ga < 4; ga++) {
    bnf_r[ga] = bnf[ga * 512 + u_c];
    bcm_r[ga] = bcm[ga * 512 + u_c];
  }
  gbar();  // h0 visible group-wide (th1 buf0 zeroed by prep)

  const size_t base1 = (size_t)N * 128;
  const size_t base2 = 2 * base1;
  const size_t base3 = base2 + (size_t)N;

  for (int t = 0; t < steps; ++t) {
    const int b_rd = (t & 1) * 8192, b_wr = b_rd ^ 8192;

    // ---- P1: gates = h(t-1) @ Whh^T + th1(t-1) @ Wcombo^T ----
    {
      const int ga = w & 3, j0 = w >> 2;
      const int tile = ga * 32 + rank * 2 + j0;
      f32x4 acc = {0.f, 0.f, 0.f, 0.f};
      const short* hA = hb_ + b_rd + lr * 512 + hi * 8;
      const short* tA = t1b + b_rd + lr * 512 + hi * 8;
      const short* wb = Wg + (size_t)tile * 16384 + l * 8;
#pragma unroll 1
      for (int kc = 0; kc < 32; ++kc) {
        s16x8 a = ld8(kc < 16 ? hA + kc * 32 : tA + (kc - 16) * 32);
        acc = mfma16(a, ld8(wb + kc * 512), acc);
      }
      for (int r = 0; r < 4; r++) gacc[ga][j0 * 16 + lr][hi * 4 + r] = acc[r];
    }
    __syncthreads();
    // ---- cell (fp32; thread owns (m_c, u_c)) ----
    {
      const float* bsel_i = t ? bcm_r : bnf_r;
      float gi = gacc[0][ul_c][m_c] + bsel_i[0];
      float gf = gacc[1][ul_c][m_c] + bsel_i[1];
      float gg = gacc[2][ul_c][m_c] + bsel_i[2];
      float go = gacc[3][ul_c][m_c] + bsel_i[3];
      float c = sigm(gf) * creg + sigm(gi) * tanhf(gg);
      creg = c;
      float h = sigm(go) * tanhf(c);
      hb_[b_wr + m_c * 512 + u_c] = (short)f2bf(h);
    }
    gbar();  // A: h(t) visible

    // ---- P2: th = tanh(h @ W1^T + b1), 6 tiles per block (waves 0..5) ----
    if (w < 6) {
      const int T2 = (w >> 1) * 32 + rank * 2 + (w & 1);
      f32x4 acc = {0.f, 0.f, 0.f, 0.f};
      const short* hA = hb_ + b_wr + lr * 512 + hi * 8;
      const short* wb = Wh + (size_t)T2 * 8192 + l * 8;
#pragma unroll 1
      for (int kc = 0; kc < 16; ++kc)
        acc = mfma16(ld8(hA + kc * 32), ld8(wb + kc * 512), acc);
      const int n = T2 * 16 + lr;
      const float bn = bh[n];
      for (int r = 0; r < 4; r++) {
        float v = tanhf(acc[r] + bn);
        int m = hi * 4 + r;
        if (T2 < 32) t1b[b_wr + m * 512 + n] = (short)f2bf(v);
        else if (T2 < 64) t2b[m * 512 + (n - 512)] = (short)f2bf(v);
        else tob[m * 512 + (n - 1024)] = (short)f2bf(v);
      }
    }
    gbar();  // B: th(t) visible

    // ---- P3 (leaf): p1 / p2 / offsets ----
    if (w == 0) {
      f32x4 acc = {0.f, 0.f, 0.f, 0.f};
      const short* aT = (rank < 8 ? t1b + b_wr : t2b) + lr * 512 + hi * 8;
      const short* wb = Wo + (size_t)rank * 8192 + l * 8;
#pragma unroll 1
      for (int kc = 0; kc < 16; ++kc)
        acc = mfma16(ld8(aT + kc * 32), ld8(wb + kc * 512), acc);
      const int nW = rank * 16 + lr;
      const float bn = bo[nW];
      for (int r = 0; r < 4; r++) {
        int m = hi * 4 + r;
        int pos = inv[t * 256 + g * 16 + m];
        if (pos >= 0) {
          float v = acc[r] + bn;
          if (rank < 8) {
            out[(size_t)pos * 128 + nW] = v;
            out[base3 + (size_t)pos * 128 + nW] = v;
          } else {
            out[base1 + (size_t)pos * 128 + (nW - 128)] = v;
          }
        }
      }
    } else if (w == 1 && rank == 0) {
      f32x4 acc = {0.f, 0.f, 0.f, 0.f};
      const short* aT = tob + lr * 512 + hi * 8;
      const short* wb = Wo + (size_t)16 * 8192 + l * 8;
#pragma unroll 1
      for (int kc = 0; kc < 16; ++kc)
        acc = mfma16(ld8(aT + kc * 32), ld8(wb + kc * 512), acc);
      if (lr == 0) {
        const float bn = bo[256];
        for (int r = 0; r < 4; r++) {
          int m = hi * 4 + r;
          int pos = inv[t * 256 + g * 16 + m];
          if (pos >= 0) out[base2 + (size_t)pos] = acc[r] + bn;
        }
      }
    }
    // no barrier here: next P1 reads buffers protected by A/B ordering
  }
}

extern "C" void kernel_launch(void* const* d_in, const int* in_sizes, int n_in,
                              void* d_out, int out_size, void* d_ws, size_t ws_size,
                              hipStream_t stream) {
  const float* features = (const float*)d_in[0];
  const float* W_f2h = (const float*)d_in[1];
  const float* b_f2h = (const float*)d_in[2];
  const float* W_ih = (const float*)d_in[3];
  const float* W_hh = (const float*)d_in[4];
  const float* b_ih = (const float*)d_in[5];
  const float* b_hh = (const float*)d_in[6];
  const float* p1W1 = (const float*)d_in[7];
  const float* p1b1 = (const float*)d_in[8];
  const float* p1W2 = (const float*)d_in[9];
  const float* p1b2 = (const float*)d_in[10];
  const float* p2W1 = (const float*)d_in[11];
  const float* p2b1 = (const float*)d_in[12];
  const float* p2W2 = (const float*)d_in[13];
  const float* p2b2 = (const float*)d_in[14];
  const float* offW1 = (const float*)d_in[15];
  const float* offb1 = (const float*)d_in[16];
  const float* offW2 = (const float*)d_in[17];
  const float* offb2 = (const float*)d_in[18];
  const int* lens = (const int*)d_in[19];
  const int* pack_idx = (const int*)d_in[20];
  const int N = in_sizes[20];
  char* ws = (char*)d_ws;
  int* inv = (int*)(ws + WS_INV);

  inv_init<<<512, 256, 0, stream>>>(inv);
  inv_fill<<<(N + 255) / 256, 256, 0, stream>>>(pack_idx, inv, N);
  // 262144 + 98304 + 17408 = 377856 fragment slots
  prep_w<<<1476, 256, 0, stream>>>(W_hh, W_ih, p1W2, p1W1, p2W1, offW1, p2W2, offW2, ws);
  // 3872 + 16384 = 20256 tasks
  prep_misc<<<80, 256, 0, stream>>>(b_ih, b_hh, W_ih, p1b2, p1b1, p2b1, offb1, p2b2,
                                    offb2, ws);
  rnn_main<<<256, 512, 0, stream>>>(features, W_f2h, b_f2h, lens, ws, inv,
                                    (float*)d_out, N);
}

// Round 6
// 14474.661 us; speedup vs baseline: 9.8703x; 1.4875x over previous
//
#include <hip/hip_runtime.h>
#include <hip/hip_bf16.h>
#include <cstddef>

// ---------------------------------------------------------------------------
// Round 6: fence-immune weights. Round-5 skeleton (validated), but:
//  - Wg (gates) weights persistent in VGPRs (128/lane, static-indexed)
//  - Wh (hidden) weights staged once into LDS
//  - A-operands bulk-staged into swizzled LDS buffers after each barrier
//  - Wo prefetched into transient regs each step
//  - inv[] replaced by offs[t]+row (provably identical for this packer)
// ---------------------------------------------------------------------------

typedef __attribute__((ext_vector_type(8))) __bf16 bf16x8;
typedef __attribute__((ext_vector_type(8))) short s16x8;
typedef __attribute__((ext_vector_type(4))) float f32x4;

static constexpr int C_BLK = 16;  // blocks per group

// ---- ws layout (bytes) — round-5 compatible ----
static constexpr size_t WS_WG = 0;         // [128 tiles][32 kc][64][8] bf16 = 4 MiB
static constexpr size_t WS_WH = 4194304;   // [96 tiles][16 kc][64][8]
static constexpr size_t WS_WO = 5767168;   // [17 tiles][16 kc][64][8]
static constexpr size_t WS_BNF = 6045696;  // float[2048]
static constexpr size_t WS_BCM = 6053888;  // float[2048]
static constexpr size_t WS_BH = 6062080;   // float[1536]
static constexpr size_t WS_BO = 6068224;   // float[272]
static constexpr size_t WS_BAR = 6070272;  // 16 * 128B
static constexpr size_t WS_OFFS = 6072320; // int[512]
static constexpr size_t WS_GRP = 6596608;  // 16 * GRPB
static constexpr size_t GRPB = 98304;
// group-internal offsets in SHORTS:
static constexpr int TH1_O = 16384;  // h [2][16][512] at 0; th1 [2][16][512]
static constexpr int TH2_O = 32768;  // th2 [16][512]
static constexpr int OFFT_O = 40960; // thoff [16][512]

// ---- dynamic LDS layout (bytes) ----
static constexpr int SM_HB = 0;       // h A-buf [16][512] bf16, swizzled
static constexpr int SM_T1 = 16384;   // th1 A-buf
static constexpr int SM_TS = 32768;   // th2/thoff section buf
static constexpr int SM_WH = 49152;   // Wh slice: 6 tiles x 16 KiB = 96 KiB
static constexpr int SM_GA = 147456;  // gacc f32 [4][32][17] = 8704
static constexpr int SM_OF = 156160;  // offs int[512]
static constexpr int SM_LN = 158208;  // lens int[16]
static constexpr int SM_SZ = 158272;

__device__ __forceinline__ unsigned short f2bf(float v) {
  __hip_bfloat16 h = __float2bfloat16(v);
  return *reinterpret_cast<unsigned short*>(&h);
}
__device__ __forceinline__ f32x4 mfma16(s16x8 a, s16x8 b, f32x4 c) {
  return __builtin_amdgcn_mfma_f32_16x16x32_bf16(
      __builtin_bit_cast(bf16x8, a), __builtin_bit_cast(bf16x8, b), c, 0, 0, 0);
}
__device__ __forceinline__ s16x8 ld8(const short* p) { return *(const s16x8*)p; }
__device__ __forceinline__ float sigm(float x) { return 1.0f / (1.0f + expf(-x)); }
// swizzled A-buffer read: row in [0,16), kb = byte offset within 1024B row
__device__ __forceinline__ s16x8 ldA(const char* base, int row, int kb) {
  return *(const s16x8*)(base + row * 1024 + (kb ^ ((row & 7) << 4)));
}

// ---------------- prep: bf16 fragment-order weights (round-5 verbatim) -------
__global__ void prep_w(const float* __restrict__ Whh, const float* __restrict__ Wih,
                       const float* __restrict__ p1W2, const float* __restrict__ p1W1,
                       const float* __restrict__ p2W1, const float* __restrict__ offW1,
                       const float* __restrict__ p2W2, const float* __restrict__ offW2,
                       char* __restrict__ ws) {
  int s = blockIdx.x * 256 + threadIdx.x;
  if (s < 262144) {  // Wg: [2048 n][1024 k] = [Whh | Wcombo=W_ih@p1W2]
    int tile = s >> 11, rem = s & 2047;
    int kc = rem >> 6, lane = rem & 63;
    int n = tile * 16 + (lane & 15);
    int k0 = kc * 32 + ((lane >> 4) << 3);
    s16x8 o;
    if (kc < 16) {
      const float* src = Whh + (size_t)n * 512 + k0;
      for (int i = 0; i < 8; i++) o[i] = (short)f2bf(src[i]);
    } else {
      int c0 = k0 - 512;
      float acc[8] = {0, 0, 0, 0, 0, 0, 0, 0};
      const float* wr = Wih + (size_t)n * 128;
      for (int j = 0; j < 128; j++) {
        float wij = wr[j];
        const float* pr = p1W2 + (size_t)j * 512 + c0;
        for (int i = 0; i < 8; i++) acc[i] += wij * pr[i];
      }
      for (int i = 0; i < 8; i++) o[i] = (short)f2bf(acc[i]);
    }
    *(s16x8*)((short*)(ws + WS_WG) + (size_t)(tile * 32 + kc) * 512 + lane * 8) = o;
  } else if (s < 262144 + 98304) {  // Wh: p1W1|p2W1|offW1
    int z = s - 262144;
    int tile = z >> 10, rem = z & 1023;
    int kc = rem >> 6, lane = rem & 63;
    int n = tile * 16 + (lane & 15);
    int k0 = kc * 32 + ((lane >> 4) << 3);
    const float* src = (n < 512) ? p1W1 + (size_t)n * 512
                     : (n < 1024) ? p2W1 + (size_t)(n - 512) * 512
                                  : offW1 + (size_t)(n - 1024) * 512;
    s16x8 o;
    for (int i = 0; i < 8; i++) o[i] = (short)f2bf(src[k0 + i]);
    *(s16x8*)((short*)(ws + WS_WH) + (size_t)(tile * 16 + kc) * 512 + lane * 8) = o;
  } else if (s < 262144 + 98304 + 17408) {  // Wo: p1W2|p2W2|offW2
    int z = s - 262144 - 98304;
    int tile = z >> 10, rem = z & 1023;
    int kc = rem >> 6, lane = rem & 63;
    int n = tile * 16 + (lane & 15);
    int k0 = kc * 32 + ((lane >> 4) << 3);
    s16x8 o;
    for (int i = 0; i < 8; i++) {
      int k = k0 + i;
      float v = (n < 128) ? p1W2[(size_t)n * 512 + k]
              : (n < 256) ? p2W2[(size_t)(n - 128) * 512 + k]
              : (n == 256) ? offW2[k] : 0.f;
      o[i] = (short)f2bf(v);
    }
    *(s16x8*)((short*)(ws + WS_WO) + (size_t)(tile * 16 + kc) * 512 + lane * 8) = o;
  }
}

// ---------------- prep: biases, barriers, packed-offset table -----------------
__global__ void prep_misc(const float* __restrict__ b_ih, const float* __restrict__ b_hh,
                          const float* __restrict__ Wih, const float* __restrict__ p1b2,
                          const float* __restrict__ p1b1, const float* __restrict__ p2b1,
                          const float* __restrict__ offb1, const float* __restrict__ p2b2,
                          const float* __restrict__ offb2, const int* __restrict__ lens,
                          char* __restrict__ ws) {
  int i = blockIdx.x * 256 + threadIdx.x;
  if (i < 2048) {
    float bn = b_ih[i] + b_hh[i];
    ((float*)(ws + WS_BNF))[i] = bn;
    float acc = 0.f;
    const float* wr = Wih + (size_t)i * 128;
    for (int j = 0; j < 128; j++) acc += wr[j] * p1b2[j];
    ((float*)(ws + WS_BCM))[i] = bn + acc;
  } else if (i < 3584) {
    int j = i - 2048;
    ((float*)(ws + WS_BH))[j] =
        j < 512 ? p1b1[j] : (j < 1024 ? p2b1[j - 512] : offb1[j - 1024]);
  } else if (i < 3856) {
    int j = i - 3584;
    ((float*)(ws + WS_BO))[j] =
        j < 128 ? p1b2[j] : (j < 256 ? p2b2[j - 128] : (j == 256 ? offb2[0] : 0.f));
  } else if (i < 3872) {
    *(int*)(ws + WS_BAR + (size_t)(i - 3856) * 128) = 0;
  } else if (i < 3872 + 512) {
    int t = i - 3872;
    int s = 0;
    for (int b = 0; b < 256; b++) { int L = lens[b]; s += (L < t ? L : t); }
    ((int*)(ws + WS_OFFS))[t] = s;
  }
}

// ---------------- main persistent kernel -------------------------------------
__launch_bounds__(512, 2)
__global__ void rnn_main(const float* __restrict__ features, const float* __restrict__ Wf2h,
                         const float* __restrict__ bf2h, const int* __restrict__ lens,
                         char* __restrict__ ws, float* __restrict__ out, int N) {
  extern __shared__ char sm[];
  const int g = blockIdx.x & 15;
  const int rank = blockIdx.x >> 4;
  const int tid = threadIdx.x, w = tid >> 6, l = tid & 63, lr = l & 15, hi = l >> 4;

  const short* Wg = (const short*)(ws + WS_WG);
  const short* Wh = (const short*)(ws + WS_WH);
  const short* Wo = (const short*)(ws + WS_WO);
  const float* bnf = (const float*)(ws + WS_BNF);
  const float* bcm = (const float*)(ws + WS_BCM);
  const float* bh = (const float*)(ws + WS_BH);
  const float* bo = (const float*)(ws + WS_BO);
  const int* offs_g = (const int*)(ws + WS_OFFS);
  int* bar = (int*)(ws + WS_BAR + (size_t)g * 128);
  short* hb_ = (short*)(ws + WS_GRP + (size_t)g * GRPB);
  short* t1b = hb_ + TH1_O;
  short* t2b = hb_ + TH2_O;
  short* tob = hb_ + OFFT_O;

  int* lens_s = (int*)(sm + SM_LN);
  int* offs_s = (int*)(sm + SM_OF);
  float* gacc = (float*)(sm + SM_GA);  // idx: (ga*32+ul)*17 + m

  if (tid < 16) lens_s[tid] = lens[g * 16 + tid];
  offs_s[tid] = offs_g[tid];  // tid in [0,512)

  // stage Wh slice (6 tiles) into LDS, once
  {
    for (int i = tid; i < 6144; i += 512) {  // 16B chunks
      int lt = i >> 10, c = i & 1023;        // c = kc*64 + lane
      int sec = lt >> 1, j = lt & 1;
      int T = sec * 32 + rank * 2 + j;
      *(s16x8*)(sm + SM_WH + (size_t)i * 16) = ld8(Wh + (size_t)T * 8192 + (size_t)c * 8);
    }
  }

  // init: h0/c0 from features, fp32 VALU (validated round 5)
  const int m_c = tid >> 5, ul_c = tid & 31, u_c = rank * 32 + ul_c;
  float creg;
  {
    const float* fr = features + (size_t)(g * 16 + m_c) * 256;
    const float* w0 = Wf2h + (size_t)(2 * u_c) * 256;
    const float* w1 = w0 + 256;
    float ah = 0.f, ac = 0.f;
    for (int k = 0; k < 256; k++) {
      float fv = fr[k];
      ah += fv * w0[k];
      ac += fv * w1[k];
    }
    ah += bf2h[2 * u_c];
    ac += bf2h[2 * u_c + 1];
    creg = ac;
    hb_[m_c * 512 + u_c] = (short)f2bf(ah);  // buffer 0
  }
  float bnf_r[4], bcm_r[4];
  for (int ga = 0; ga < 4; ga++) {
    bnf_r[ga] = bnf[ga * 512 + u_c];
    bcm_r[ga] = bcm[ga * 512 + u_c];
  }
  // per-wave persistent P1 weights: 32 x s16x8 = 128 VGPRs
  const int ga_w = w & 3, j0_w = w >> 2;
  const int tileG = ga_w * 32 + rank * 2 + j0_w;
  s16x8 wgr[32];
  {
    const short* wb = Wg + (size_t)tileG * 16384 + l * 8;
#pragma unroll
    for (int kc = 0; kc < 32; ++kc) wgr[kc] = ld8(wb + (size_t)kc * 512);
  }
  // P2 constants
  const int secw = w >> 1;
  const int T2 = secw * 32 + rank * 2 + (w & 1);
  const int lt2 = secw * 2 + (w & 1);
  float bh_r = (w < 6) ? bh[T2 * 16 + lr] : 0.f;
  float bo_r = (w == 0) ? bo[rank * 16 + lr] : ((w == 1 && rank == 7) ? bo[256] : 0.f);

  int steps = 0;
  __syncthreads();
  for (int i = 0; i < 16; i++) steps = max(steps, lens_s[i]);

  int ep = 0;
  auto gbar = [&]() {
    __syncthreads();
    if (tid == 0) {
      ++ep;
      __threadfence();
      __hip_atomic_fetch_add(bar, 1, __ATOMIC_RELEASE, __HIP_MEMORY_SCOPE_AGENT);
      while (__hip_atomic_load(bar, __ATOMIC_ACQUIRE, __HIP_MEMORY_SCOPE_AGENT) <
             ep * C_BLK)
        __builtin_amdgcn_s_sleep(1);
      __threadfence();
    }
    __syncthreads();
  };

  // bulk A-staging: 16 KB global -> swizzled LDS buffer
  auto stageA = [&](char* dst, const short* src) {
#pragma unroll
    for (int q = 0; q < 2; ++q) {
      int j = tid + q * 512;           // 16B chunk index in [0,1024)
      int row = j >> 6, kb = (j & 63) << 4;
      *(s16x8*)(dst + row * 1024 + (kb ^ ((row & 7) << 4))) = ld8(src + (size_t)j * 8);
    }
  };

  gbar();  // h0 visible group-wide
  stageA(sm + SM_HB, hb_);  // h(-1)=h0
  {  // th1(-1) = 0
    s16x8 zz = {0, 0, 0, 0, 0, 0, 0, 0};
#pragma unroll
    for (int q = 0; q < 2; ++q) {
      int j = tid + q * 512;
      int row = j >> 6, kb = (j & 63) << 4;
      *(s16x8*)(sm + SM_T1 + row * 1024 + (kb ^ ((row & 7) << 4))) = zz;
    }
  }
  __syncthreads();

  const size_t base1 = (size_t)N * 128;
  const size_t base2 = 2 * base1;
  const size_t base3 = base2 + (size_t)N;

  // P3 for step tt (uses SM_T1 / SM_TS which hold th(tt) when called)
  auto doP3 = [&](int tt) {
    if (tt < 0) return;
    const int offs_t = offs_s[tt];
    if (w == 0) {
      s16x8 wo[16];
      const short* wb = Wo + (size_t)(rank * 16) * 512 + l * 8;
#pragma unroll
      for (int kc = 0; kc < 16; ++kc) wo[kc] = ld8(wb + (size_t)kc * 512);
      f32x4 acc = {0.f, 0.f, 0.f, 0.f};
      const char* ab = sm + (rank < 8 ? SM_T1 : SM_TS);
#pragma unroll
      for (int kc = 0; kc < 16; ++kc)
        acc = mfma16(ldA(ab, lr, kc * 64 + hi * 16), wo[kc], acc);
      const int nW = rank * 16 + lr;
      for (int r = 0; r < 4; r++) {
        int m = hi * 4 + r;
        if (tt < lens_s[m]) {
          size_t pos = (size_t)(offs_t + g * 16 + m);
          float v = acc[r] + bo_r;
          if (rank < 8) {
            out[pos * 128 + nW] = v;
            out[base3 + pos * 128 + nW] = v;
          } else {
            out[base1 + pos * 128 + (nW - 128)] = v;
          }
        }
      }
    } else if (w == 1 && rank == 7) {
      s16x8 wo[16];
      const short* wb = Wo + (size_t)(16 * 16) * 512 + l * 8;
#pragma unroll
      for (int kc = 0; kc < 16; ++kc) wo[kc] = ld8(wb + (size_t)kc * 512);
      f32x4 acc = {0.f, 0.f, 0.f, 0.f};
#pragma unroll
      for (int kc = 0; kc < 16; ++kc)
        acc = mfma16(ldA(sm + SM_TS, lr, kc * 64 + hi * 16), wo[kc], acc);
      if (lr == 0) {
        for (int r = 0; r < 4; r++) {
          int m = hi * 4 + r;
          if (tt < lens_s[m])
            out[base2 + (size_t)(offs_s[tt] + g * 16 + m)] = acc[r] + bo_r;
        }
      }
    }
  };

  for (int t = 0; t < steps; ++t) {
    const int b_wr = ((t & 1) * 8192) ^ 8192;

    // ---- P1: gates from SM_HB (h(t-1)) + SM_T1 (th1(t-1)), weights in VGPRs ----
    {
      f32x4 acc = {0.f, 0.f, 0.f, 0.f};
#pragma unroll
      for (int kc = 0; kc < 16; ++kc)
        acc = mfma16(ldA(sm + SM_HB, lr, kc * 64 + hi * 16), wgr[kc], acc);
#pragma unroll
      for (int kc = 0; kc < 16; ++kc)
        acc = mfma16(ldA(sm + SM_T1, lr, kc * 64 + hi * 16), wgr[16 + kc], acc);
      for (int r = 0; r < 4; r++)
        gacc[(ga_w * 32 + j0_w * 16 + lr) * 17 + hi * 4 + r] = acc[r];
    }
    // ---- P3 for previous step (reads SM_T1 / SM_TS, th(t-1)) ----
    doP3(t - 1);
    __syncthreads();

    // ---- cell (fp32), write h(t) to global ----
    {
      const float* bsel = t ? bcm_r : bnf_r;
      float gi = gacc[(0 * 32 + ul_c) * 17 + m_c] + bsel[0];
      float gf = gacc[(1 * 32 + ul_c) * 17 + m_c] + bsel[1];
      float gg = gacc[(2 * 32 + ul_c) * 17 + m_c] + bsel[2];
      float go = gacc[(3 * 32 + ul_c) * 17 + m_c] + bsel[3];
      float c = sigm(gf) * creg + sigm(gi) * tanhf(gg);
      creg = c;
      float h = sigm(go) * tanhf(c);
      hb_[b_wr + m_c * 512 + u_c] = (short)f2bf(h);
    }
    gbar();  // A: h(t) visible

    stageA(sm + SM_HB, hb_ + b_wr);  // SM_HB := h(t)
    __syncthreads();

    // ---- P2: th = tanh(h(t) @ W1^T + b1); weights from LDS ----
    if (w < 6) {
      f32x4 acc = {0.f, 0.f, 0.f, 0.f};
      const char* wl = sm + SM_WH + lt2 * 16384 + l * 16;
#pragma unroll
      for (int kc = 0; kc < 16; ++kc)
        acc = mfma16(ldA(sm + SM_HB, lr, kc * 64 + hi * 16),
                     *(const s16x8*)(wl + kc * 1024), acc);
      const int n = T2 * 16 + lr;
      for (int r = 0; r < 4; r++) {
        float v = tanhf(acc[r] + bh_r);
        int m = hi * 4 + r;
        if (T2 < 32) t1b[b_wr + m * 512 + n] = (short)f2bf(v);
        else if (T2 < 64) t2b[m * 512 + (n - 512)] = (short)f2bf(v);
        else tob[m * 512 + (n - 1024)] = (short)f2bf(v);
      }
    }
    gbar();  // B: th(t) visible

    // ---- stage th1(t) (+ section for P3) ----
    stageA(sm + SM_T1, t1b + b_wr);
    if (rank >= 7) stageA(sm + SM_TS, rank == 7 ? tob : t2b);
    __syncthreads();
  }
  doP3(steps - 1);
}

extern "C" void kernel_launch(void* const* d_in, const int* in_sizes, int n_in,
                              void* d_out, int out_size, void* d_ws, size_t ws_size,
                              hipStream_t stream) {
  const float* features = (const float*)d_in[0];
  const float* W_f2h = (const float*)d_in[1];
  const float* b_f2h = (const float*)d_in[2];
  const float* W_ih = (const float*)d_in[3];
  const float* W_hh = (const float*)d_in[4];
  const float* b_ih = (const float*)d_in[5];
  const float* b_hh = (const float*)d_in[6];
  const float* p1W1 = (const float*)d_in[7];
  const float* p1b1 = (const float*)d_in[8];
  const float* p1W2 = (const float*)d_in[9];
  const float* p1b2 = (const float*)d_in[10];
  const float* p2W1 = (const float*)d_in[11];
  const float* p2b1 = (const float*)d_in[12];
  const float* p2W2 = (const float*)d_in[13];
  const float* p2b2 = (const float*)d_in[14];
  const float* offW1 = (const float*)d_in[15];
  const float* offb1 = (const float*)d_in[16];
  const float* offW2 = (const float*)d_in[17];
  const float* offb2 = (const float*)d_in[18];
  const int* lens = (const int*)d_in[19];
  const int N = in_sizes[20];
  char* ws = (char*)d_ws;

  prep_w<<<1476, 256, 0, stream>>>(W_hh, W_ih, p1W2, p1W1, p2W1, offW1, p2W2, offW2, ws);
  prep_misc<<<18, 256, 0, stream>>>(b_ih, b_hh, W_ih, p1b2, p1b1, p2b1, offb1, p2b2,
                                    offb2, lens, ws);
  (void)hipFuncSetAttribute((const void*)rnn_main,
                            hipFuncAttributeMaxDynamicSharedMemorySize, SM_SZ);
  rnn_main<<<256, 512, SM_SZ, stream>>>(features, W_f2h, b_f2h, lens, ws,
                                        (float*)d_out, N);
}

// Round 7
// 5381.771 us; speedup vs baseline: 26.5468x; 2.6896x over previous
//
#include <hip/hip_runtime.h>
#include <hip/hip_bf16.h>
#include <cstddef>

// ---------------------------------------------------------------------------
// Round 7: fence-free group barriers + cache-bypassing state exchange.
// All cross-block state moves via RELAXED agent-scope atomics (sc0/sc1 path,
// no buffer_wbl2/buffer_inv). Barrier = relaxed fetch_add + relaxed poll.
// Stage latencies hidden under P3(t-1) and P1(t+1)-h-half MFMA.
// Skeleton, weights-in-VGPR/LDS, packing, and math identical to round 6.
// ---------------------------------------------------------------------------

typedef __attribute__((ext_vector_type(8))) __bf16 bf16x8;
typedef __attribute__((ext_vector_type(8))) short s16x8;
typedef __attribute__((ext_vector_type(4))) float f32x4;
typedef unsigned long long u64;
typedef unsigned int u32;

static constexpr int C_BLK = 16;

// ---- ws layout (bytes) ----
static constexpr size_t WS_WG = 0;
static constexpr size_t WS_WH = 4194304;
static constexpr size_t WS_WO = 5767168;
static constexpr size_t WS_BNF = 6045696;
static constexpr size_t WS_BCM = 6053888;
static constexpr size_t WS_BH = 6062080;
static constexpr size_t WS_BO = 6068224;
static constexpr size_t WS_BAR = 6070272;
static constexpr size_t WS_OFFS = 6072320;
static constexpr size_t WS_GRP = 6596608;
static constexpr size_t GRPB = 98304;
// group-internal offsets in SHORTS
static constexpr int TH1_O = 16384;
static constexpr int TH2_O = 32768;
static constexpr int OFFT_O = 40960;

// ---- dynamic LDS (bytes) ----
static constexpr int SM_HB = 0;
static constexpr int SM_T1 = 16384;
static constexpr int SM_TS = 32768;   // also aliased as P2 scratch (3 KB)
static constexpr int SM_WH = 49152;
static constexpr int SM_GA = 147456;  // f32 gacc (ga*32+ul)*17+m
static constexpr int SM_OF = 156160;
static constexpr int SM_LN = 158208;
static constexpr int SM_SZ = 158272;

__device__ __forceinline__ unsigned short f2bf(float v) {
  __hip_bfloat16 h = __float2bfloat16(v);
  return *reinterpret_cast<unsigned short*>(&h);
}
__device__ __forceinline__ f32x4 mfma16(s16x8 a, s16x8 b, f32x4 c) {
  return __builtin_amdgcn_mfma_f32_16x16x32_bf16(
      __builtin_bit_cast(bf16x8, a), __builtin_bit_cast(bf16x8, b), c, 0, 0, 0);
}
__device__ __forceinline__ s16x8 ld8(const short* p) { return *(const s16x8*)p; }
__device__ __forceinline__ float sigm(float x) { return 1.0f / (1.0f + expf(-x)); }
__device__ __forceinline__ s16x8 ldA(const char* base, int row, int kb) {
  return *(const s16x8*)(base + row * 1024 + (kb ^ ((row & 7) << 4)));
}
__device__ __forceinline__ u64 ldc(const u64* p) {  // coherent (bypassing) load
  return __hip_atomic_load(p, __ATOMIC_RELAXED, __HIP_MEMORY_SCOPE_AGENT);
}
__device__ __forceinline__ void stc(u32* p, u32 v) {  // coherent store
  __hip_atomic_store(p, v, __ATOMIC_RELAXED, __HIP_MEMORY_SCOPE_AGENT);
}

// ---------------- prep kernels (validated, round-6 verbatim) ------------------
__global__ void prep_w(const float* __restrict__ Whh, const float* __restrict__ Wih,
                       const float* __restrict__ p1W2, const float* __restrict__ p1W1,
                       const float* __restrict__ p2W1, const float* __restrict__ offW1,
                       const float* __restrict__ p2W2, const float* __restrict__ offW2,
                       char* __restrict__ ws) {
  int s = blockIdx.x * 256 + threadIdx.x;
  if (s < 262144) {
    int tile = s >> 11, rem = s & 2047;
    int kc = rem >> 6, lane = rem & 63;
    int n = tile * 16 + (lane & 15);
    int k0 = kc * 32 + ((lane >> 4) << 3);
    s16x8 o;
    if (kc < 16) {
      const float* src = Whh + (size_t)n * 512 + k0;
      for (int i = 0; i < 8; i++) o[i] = (short)f2bf(src[i]);
    } else {
      int c0 = k0 - 512;
      float acc[8] = {0, 0, 0, 0, 0, 0, 0, 0};
      const float* wr = Wih + (size_t)n * 128;
      for (int j = 0; j < 128; j++) {
        float wij = wr[j];
        const float* pr = p1W2 + (size_t)j * 512 + c0;
        for (int i = 0; i < 8; i++) acc[i] += wij * pr[i];
      }
      for (int i = 0; i < 8; i++) o[i] = (short)f2bf(acc[i]);
    }
    *(s16x8*)((short*)(ws + WS_WG) + (size_t)(tile * 32 + kc) * 512 + lane * 8) = o;
  } else if (s < 262144 + 98304) {
    int z = s - 262144;
    int tile = z >> 10, rem = z & 1023;
    int kc = rem >> 6, lane = rem & 63;
    int n = tile * 16 + (lane & 15);
    int k0 = kc * 32 + ((lane >> 4) << 3);
    const float* src = (n < 512) ? p1W1 + (size_t)n * 512
                     : (n < 1024) ? p2W1 + (size_t)(n - 512) * 512
                                  : offW1 + (size_t)(n - 1024) * 512;
    s16x8 o;
    for (int i = 0; i < 8; i++) o[i] = (short)f2bf(src[k0 + i]);
    *(s16x8*)((short*)(ws + WS_WH) + (size_t)(tile * 16 + kc) * 512 + lane * 8) = o;
  } else if (s < 262144 + 98304 + 17408) {
    int z = s - 262144 - 98304;
    int tile = z >> 10, rem = z & 1023;
    int kc = rem >> 6, lane = rem & 63;
    int n = tile * 16 + (lane & 15);
    int k0 = kc * 32 + ((lane >> 4) << 3);
    s16x8 o;
    for (int i = 0; i < 8; i++) {
      int k = k0 + i;
      float v = (n < 128) ? p1W2[(size_t)n * 512 + k]
              : (n < 256) ? p2W2[(size_t)(n - 128) * 512 + k]
              : (n == 256) ? offW2[k] : 0.f;
      o[i] = (short)f2bf(v);
    }
    *(s16x8*)((short*)(ws + WS_WO) + (size_t)(tile * 16 + kc) * 512 + lane * 8) = o;
  }
}

__global__ void prep_misc(const float* __restrict__ b_ih, const float* __restrict__ b_hh,
                          const float* __restrict__ Wih, const float* __restrict__ p1b2,
                          const float* __restrict__ p1b1, const float* __restrict__ p2b1,
                          const float* __restrict__ offb1, const float* __restrict__ p2b2,
                          const float* __restrict__ offb2, const int* __restrict__ lens,
                          char* __restrict__ ws) {
  int i = blockIdx.x * 256 + threadIdx.x;
  if (i < 2048) {
    float bn = b_ih[i] + b_hh[i];
    ((float*)(ws + WS_BNF))[i] = bn;
    float acc = 0.f;
    const float* wr = Wih + (size_t)i * 128;
    for (int j = 0; j < 128; j++) acc += wr[j] * p1b2[j];
    ((float*)(ws + WS_BCM))[i] = bn + acc;
  } else if (i < 3584) {
    int j = i - 2048;
    ((float*)(ws + WS_BH))[j] =
        j < 512 ? p1b1[j] : (j < 1024 ? p2b1[j - 512] : offb1[j - 1024]);
  } else if (i < 3856) {
    int j = i - 3584;
    ((float*)(ws + WS_BO))[j] =
        j < 128 ? p1b2[j] : (j < 256 ? p2b2[j - 128] : (j == 256 ? offb2[0] : 0.f));
  } else if (i < 3872) {
    *(int*)(ws + WS_BAR + (size_t)(i - 3856) * 128) = 0;
  } else if (i < 3872 + 512) {
    int t = i - 3872;
    int s = 0;
    for (int b = 0; b < 256; b++) { int L = lens[b]; s += (L < t ? L : t); }
    ((int*)(ws + WS_OFFS))[t] = s;
  }
}

// ---------------- main persistent kernel -------------------------------------
__launch_bounds__(512, 2)
__global__ void rnn_main(const float* __restrict__ features, const float* __restrict__ Wf2h,
                         const float* __restrict__ bf2h, const int* __restrict__ lens,
                         char* __restrict__ ws, float* __restrict__ out, int N) {
  extern __shared__ char sm[];
  const int g = blockIdx.x & 15;
  const int rank = blockIdx.x >> 4;
  const int tid = threadIdx.x, w = tid >> 6, l = tid & 63, lr = l & 15, hi = l >> 4;

  const short* Wg = (const short*)(ws + WS_WG);
  const short* Wh = (const short*)(ws + WS_WH);
  const short* Wo = (const short*)(ws + WS_WO);
  const float* bnf = (const float*)(ws + WS_BNF);
  const float* bcm = (const float*)(ws + WS_BCM);
  const float* bh = (const float*)(ws + WS_BH);
  const float* bo = (const float*)(ws + WS_BO);
  const int* offs_g = (const int*)(ws + WS_OFFS);
  int* bar = (int*)(ws + WS_BAR + (size_t)g * 128);
  short* hb_ = (short*)(ws + WS_GRP + (size_t)g * GRPB);
  short* t1b = hb_ + TH1_O;
  short* t2b = hb_ + TH2_O;
  short* tob = hb_ + OFFT_O;

  int* lens_s = (int*)(sm + SM_LN);
  int* offs_s = (int*)(sm + SM_OF);
  float* gacc = (float*)(sm + SM_GA);
  short* scratch = (short*)(sm + SM_TS);  // P2 staging [3][16][32] shorts

  if (tid < 16) lens_s[tid] = lens[g * 16 + tid];
  offs_s[tid] = offs_g[tid];

  // stage Wh slice into LDS (once)
  for (int i = tid; i < 6144; i += 512) {
    int lt = i >> 10, c = i & 1023;
    int sec = lt >> 1, j = lt & 1;
    int T = sec * 32 + rank * 2 + j;
    *(s16x8*)(sm + SM_WH + (size_t)i * 16) = ld8(Wh + (size_t)T * 8192 + (size_t)c * 8);
  }

  // ---- init: h0/c0, threads 0..255, 2 adjacent units each ----
  const int m_c = tid >> 4, p_c = tid & 15;        // row, unit-pair
  const int u0 = rank * 32 + 2 * p_c;
  float creg0 = 0.f, creg1 = 0.f;
  float bn0[4], bn1[4], bc0[4], bc1[4];
  if (tid < 256) {
    const float* fr = features + (size_t)(g * 16 + m_c) * 256;
    const float* wa = Wf2h + (size_t)(2 * u0) * 256;
    float ah0 = 0.f, ac0 = 0.f, ah1 = 0.f, ac1 = 0.f;
    for (int k = 0; k < 256; k++) {
      float fv = fr[k];
      ah0 += fv * wa[k];
      ac0 += fv * wa[256 + k];
      ah1 += fv * wa[512 + k];
      ac1 += fv * wa[768 + k];
    }
    ah0 += bf2h[2 * u0];     ac0 += bf2h[2 * u0 + 1];
    ah1 += bf2h[2 * u0 + 2]; ac1 += bf2h[2 * u0 + 3];
    creg0 = ac0; creg1 = ac1;
    u32 pk = (u32)f2bf(ah0) | ((u32)f2bf(ah1) << 16);
    stc((u32*)hb_ + m_c * 256 + rank * 16 + p_c, pk);  // buffer 0
    for (int ga = 0; ga < 4; ga++) {
      bn0[ga] = bnf[ga * 512 + u0];     bn1[ga] = bnf[ga * 512 + u0 + 1];
      bc0[ga] = bcm[ga * 512 + u0];     bc1[ga] = bcm[ga * 512 + u0 + 1];
    }
  }

  // per-wave persistent gates weights (32 x s16x8)
  const int ga_w = w & 3, j0_w = w >> 2;
  const int tileG = ga_w * 32 + rank * 2 + j0_w;
  s16x8 wgr[32];
  {
    const short* wb = Wg + (size_t)tileG * 16384 + l * 8;
#pragma unroll
    for (int kc = 0; kc < 32; ++kc) wgr[kc] = ld8(wb + (size_t)kc * 512);
  }
  const int secw = w >> 1;
  const int T2 = secw * 32 + rank * 2 + (w & 1);
  const int lt2 = secw * 2 + (w & 1);
  float bh_r = (w < 6) ? bh[T2 * 16 + lr] : 0.f;
  float bo_r = (w == 0) ? bo[rank * 16 + lr] : ((w == 1 && rank == 7) ? bo[256] : 0.f);

  int steps = 0;
  __syncthreads();
  for (int i = 0; i < 16; i++) steps = max(steps, lens_s[i]);

  int ep = 0;
  auto gbar = [&]() {
    asm volatile("s_waitcnt vmcnt(0)" ::: "memory");
    __syncthreads();
    ++ep;
    if (tid == 0) {
      __hip_atomic_fetch_add(bar, 1, __ATOMIC_RELAXED, __HIP_MEMORY_SCOPE_AGENT);
      while (__hip_atomic_load(bar, __ATOMIC_RELAXED, __HIP_MEMORY_SCOPE_AGENT) <
             ep * C_BLK)
        __builtin_amdgcn_s_sleep(2);
    }
    __syncthreads();
  };

  const size_t base1 = (size_t)N * 128;
  const size_t base2 = 2 * base1;
  const size_t base3 = base2 + (size_t)N;

  auto doP3 = [&](int tt) {  // reads SM_T1 / SM_TS (th of step tt)
    if (tt < 0) return;
    const int offs_t = offs_s[tt];
    if (w == 0) {
      s16x8 wo[16];
      const short* wb = Wo + (size_t)(rank * 16) * 512 + l * 8;
#pragma unroll
      for (int kc = 0; kc < 16; ++kc) wo[kc] = ld8(wb + (size_t)kc * 512);
      f32x4 acc = {0.f, 0.f, 0.f, 0.f};
      const char* ab = sm + (rank < 8 ? SM_T1 : SM_TS);
#pragma unroll
      for (int kc = 0; kc < 16; ++kc)
        acc = mfma16(ldA(ab, lr, kc * 64 + hi * 16), wo[kc], acc);
      const int nW = rank * 16 + lr;
      for (int r = 0; r < 4; r++) {
        int m = hi * 4 + r;
        if (tt < lens_s[m]) {
          size_t pos = (size_t)(offs_t + g * 16 + m);
          float v = acc[r] + bo_r;
          if (rank < 8) {
            out[pos * 128 + nW] = v;
            out[base3 + pos * 128 + nW] = v;
          } else {
            out[base1 + pos * 128 + (nW - 128)] = v;
          }
        }
      }
    } else if (w == 1 && rank == 7) {
      s16x8 wo[16];
      const short* wb = Wo + (size_t)(16 * 16) * 512 + l * 8;
#pragma unroll
      for (int kc = 0; kc < 16; ++kc) wo[kc] = ld8(wb + (size_t)kc * 512);
      f32x4 acc = {0.f, 0.f, 0.f, 0.f};
#pragma unroll
      for (int kc = 0; kc < 16; ++kc)
        acc = mfma16(ldA(sm + SM_TS, lr, kc * 64 + hi * 16), wo[kc], acc);
      if (lr == 0) {
        for (int r = 0; r < 4; r++) {
          int m = hi * 4 + r;
          if (tt < lens_s[m])
            out[base2 + (size_t)(offs_t + g * 16 + m)] = acc[r] + bo_r;
        }
      }
    }
  };

  // chunk geometry for 16KB stages: chunk j -> row j>>6, kb (j&63)<<4
  const int j0c = tid, j1c = tid + 512;
  const int r0 = j0c >> 6, k0b = (j0c & 63) << 4;
  const int r1 = j1c >> 6, k1b = (j1c & 63) << 4;
  char* d0h = sm + SM_HB + r0 * 1024 + (k0b ^ ((r0 & 7) << 4));
  char* d1h = sm + SM_HB + r1 * 1024 + (k1b ^ ((r1 & 7) << 4));
  char* d0t = sm + SM_T1 + r0 * 1024 + (k0b ^ ((r0 & 7) << 4));
  char* d1t = sm + SM_T1 + r1 * 1024 + (k1b ^ ((r1 & 7) << 4));
  char* d0s = sm + SM_TS + r0 * 1024 + (k0b ^ ((r0 & 7) << 4));
  char* d1s = sm + SM_TS + r1 * 1024 + (k1b ^ ((r1 & 7) << 4));

  gbar();  // h0 published group-wide

  // prologue: stage SM_HB = h0; SM_T1 = 0
  {
    const u64* hq = (const u64*)hb_;
    u64 a0 = ldc(hq + 2 * j0c), b0 = ldc(hq + 2 * j0c + 1);
    u64 a1 = ldc(hq + 2 * j1c), b1 = ldc(hq + 2 * j1c + 1);
    *(u64*)d0h = a0; *(u64*)(d0h + 8) = b0;
    *(u64*)d1h = a1; *(u64*)(d1h + 8) = b1;
    *(u64*)d0t = 0ull; *(u64*)(d0t + 8) = 0ull;
    *(u64*)d1t = 0ull; *(u64*)(d1t + 8) = 0ull;
  }
  __syncthreads();
  f32x4 accP1 = {0.f, 0.f, 0.f, 0.f};  // h-half of next gates
#pragma unroll
  for (int kc = 0; kc < 16; ++kc)
    accP1 = mfma16(ldA(sm + SM_HB, lr, kc * 64 + hi * 16), wgr[kc], accP1);

  for (int t = 0; t < steps; ++t) {
    const int b_wr = ((t & 1) * 8192) ^ 8192;  // h(t)/th1(t) buffer (shorts)

    // ---- P1 finish: + th1(t-1) half ----
    {
      f32x4 acc = accP1;
#pragma unroll
      for (int kc = 0; kc < 16; ++kc)
        acc = mfma16(ldA(sm + SM_T1, lr, kc * 64 + hi * 16), wgr[16 + kc], acc);
      for (int r = 0; r < 4; r++)
        gacc[(ga_w * 32 + j0_w * 16 + lr) * 17 + hi * 4 + r] = acc[r];
    }
    __syncthreads();

    // ---- cell (threads 0..255; 2 units each), publish h(t) ----
    if (tid < 256) {
      const int ua = 2 * p_c;
      float gi0 = gacc[(0 * 32 + ua) * 17 + m_c] + (t ? bc0[0] : bn0[0]);
      float gf0 = gacc[(1 * 32 + ua) * 17 + m_c] + (t ? bc0[1] : bn0[1]);
      float gg0 = gacc[(2 * 32 + ua) * 17 + m_c] + (t ? bc0[2] : bn0[2]);
      float go0 = gacc[(3 * 32 + ua) * 17 + m_c] + (t ? bc0[3] : bn0[3]);
      float gi1 = gacc[(0 * 32 + ua + 1) * 17 + m_c] + (t ? bc1[0] : bn1[0]);
      float gf1 = gacc[(1 * 32 + ua + 1) * 17 + m_c] + (t ? bc1[1] : bn1[1]);
      float gg1 = gacc[(2 * 32 + ua + 1) * 17 + m_c] + (t ? bc1[2] : bn1[2]);
      float go1 = gacc[(3 * 32 + ua + 1) * 17 + m_c] + (t ? bc1[3] : bn1[3]);
      float c0 = sigm(gf0) * creg0 + sigm(gi0) * tanhf(gg0);
      float c1 = sigm(gf1) * creg1 + sigm(gi1) * tanhf(gg1);
      creg0 = c0; creg1 = c1;
      float h0 = sigm(go0) * tanhf(c0);
      float h1 = sigm(go1) * tanhf(c1);
      u32 pk = (u32)f2bf(h0) | ((u32)f2bf(h1) << 16);
      stc((u32*)hb_ + (b_wr >> 1) + m_c * 256 + rank * 16 + p_c, pk);
    }
    gbar();  // A: h(t) at coherence point

    // ---- stage h(t) (loads issued, P3(t-1) hides latency) ----
    {
      const u64* hq = (const u64*)hb_ + (b_wr >> 2);
      u64 a0 = ldc(hq + 2 * j0c), b0 = ldc(hq + 2 * j0c + 1);
      u64 a1 = ldc(hq + 2 * j1c), b1 = ldc(hq + 2 * j1c + 1);
      doP3(t - 1);
      *(u64*)d0h = a0; *(u64*)(d0h + 8) = b0;
      *(u64*)d1h = a1; *(u64*)(d1h + 8) = b1;
    }
    __syncthreads();

    // ---- P2: th(t) = tanh(h(t) @ W1^T + b1) -> LDS scratch ----
    if (w < 6) {
      f32x4 acc = {0.f, 0.f, 0.f, 0.f};
      const char* wl = sm + SM_WH + lt2 * 16384 + l * 16;
#pragma unroll
      for (int kc = 0; kc < 16; ++kc)
        acc = mfma16(ldA(sm + SM_HB, lr, kc * 64 + hi * 16),
                     *(const s16x8*)(wl + kc * 1024), acc);
      for (int r = 0; r < 4; r++) {
        float v = tanhf(acc[r] + bh_r);
        int m = hi * 4 + r;
        scratch[(secw * 16 + m) * 32 + ((w & 1) << 4) + lr] = (short)f2bf(v);
      }
    }
    __syncthreads();
    // ---- publish th(t): threads 0..255, one u32 per section ----
    if (tid < 256) {
      u32 v0 = *(const u32*)(scratch + (0 * 16 + m_c) * 32 + 2 * p_c);
      u32 v1 = *(const u32*)(scratch + (1 * 16 + m_c) * 32 + 2 * p_c);
      u32 v2 = *(const u32*)(scratch + (2 * 16 + m_c) * 32 + 2 * p_c);
      int wi = m_c * 256 + rank * 16 + p_c;
      stc((u32*)t1b + (b_wr >> 1) + wi, v0);
      stc((u32*)t2b + wi, v1);
      stc((u32*)tob + wi, v2);
    }
    gbar();  // B: th(t) at coherence point

    // ---- stage th1(t) (+TS) with P1(t+1) h-half hiding latency ----
    {
      const u64* tq = (const u64*)t1b + (b_wr >> 2);
      u64 a0 = ldc(tq + 2 * j0c), b0 = ldc(tq + 2 * j0c + 1);
      u64 a1 = ldc(tq + 2 * j1c), b1 = ldc(tq + 2 * j1c + 1);
      u64 sa0 = 0, sb0 = 0, sa1 = 0, sb1 = 0;
      if (rank >= 7) {
        const u64* sq = (const u64*)(rank == 7 ? tob : t2b);
        sa0 = ldc(sq + 2 * j0c); sb0 = ldc(sq + 2 * j0c + 1);
        sa1 = ldc(sq + 2 * j1c); sb1 = ldc(sq + 2 * j1c + 1);
      }
      f32x4 acc = {0.f, 0.f, 0.f, 0.f};
#pragma unroll
      for (int kc = 0; kc < 16; ++kc)
        acc = mfma16(ldA(sm + SM_HB, lr, kc * 64 + hi * 16), wgr[kc], acc);
      accP1 = acc;
      *(u64*)d0t = a0; *(u64*)(d0t + 8) = b0;
      *(u64*)d1t = a1; *(u64*)(d1t + 8) = b1;
      if (rank >= 7) {
        *(u64*)d0s = sa0; *(u64*)(d0s + 8) = sb0;
        *(u64*)d1s = sa1; *(u64*)(d1s + 8) = sb1;
      }
    }
    __syncthreads();
  }
  doP3(steps - 1);
}

extern "C" void kernel_launch(void* const* d_in, const int* in_sizes, int n_in,
                              void* d_out, int out_size, void* d_ws, size_t ws_size,
                              hipStream_t stream) {
  const float* features = (const float*)d_in[0];
  const float* W_f2h = (const float*)d_in[1];
  const float* b_f2h = (const float*)d_in[2];
  const float* W_ih = (const float*)d_in[3];
  const float* W_hh = (const float*)d_in[4];
  const float* b_ih = (const float*)d_in[5];
  const float* b_hh = (const float*)d_in[6];
  const float* p1W1 = (const float*)d_in[7];
  const float* p1b1 = (const float*)d_in[8];
  const float* p1W2 = (const float*)d_in[9];
  const float* p1b2 = (const float*)d_in[10];
  const float* p2W1 = (const float*)d_in[11];
  const float* p2b1 = (const float*)d_in[12];
  const float* p2W2 = (const float*)d_in[13];
  const float* p2b2 = (const float*)d_in[14];
  const float* offW1 = (const float*)d_in[15];
  const float* offb1 = (const float*)d_in[16];
  const float* offW2 = (const float*)d_in[17];
  const float* offb2 = (const float*)d_in[18];
  const int* lens = (const int*)d_in[19];
  const int N = in_sizes[20];
  char* ws = (char*)d_ws;

  prep_w<<<1476, 256, 0, stream>>>(W_hh, W_ih, p1W2, p1W1, p2W1, offW1, p2W2, offW2, ws);
  prep_misc<<<18, 256, 0, stream>>>(b_ih, b_hh, W_ih, p1b2, p1b1, p2b1, offb1, p2b2,
                                    offb2, lens, ws);
  (void)hipFuncSetAttribute((const void*)rnn_main,
                            hipFuncAttributeMaxDynamicSharedMemorySize, SM_SZ);
  rnn_main<<<256, 512, SM_SZ, stream>>>(features, W_f2h, b_f2h, lens, ws,
                                        (float*)d_out, N);
}